// Round 8
// baseline (268.343 us; speedup 1.0000x reference)
//
#include <hip/hip_runtime.h>

#define DIM   1024
#define NH    16
#define HD    64
#define BATCH 16
#define SEQ   512
#define MROWS (BATCH*SEQ)   // 8192
#define SL2E  0.18033688011112042f   // 0.125 * log2(e)

typedef __bf16 bf16x8 __attribute__((ext_vector_type(8)));
typedef float  floatx4 __attribute__((ext_vector_type(4)));
typedef short  short4v __attribute__((ext_vector_type(4)));

static __device__ __forceinline__ unsigned short f2bf(float f) {
    union { float f; unsigned u; } v; v.f = f;
    return (unsigned short)((v.u + 0x8000u) >> 16);
}
static __device__ __forceinline__ unsigned pk2(float a, float b) {
    union { float f; unsigned u; } x, y; x.f = a; y.f = b;
    return ((x.u + 0x8000u) >> 16) | ((y.u + 0x8000u) & 0xffff0000u);
}

static __device__ __forceinline__ void glds16(const void* g, void* l) {
    __builtin_amdgcn_global_load_lds(
        (const __attribute__((address_space(1))) unsigned int*)g,
        (__attribute__((address_space(3))) unsigned int*)l, 16, 0, 0);
}

// ---------------------------------------------------------------------------
// Fused prep: [0,8192) cvt x/ctx -> bf16 ; [8192,12288) transpose 4 weights ;
// [12288,12416) RoPE cos/sin table (interleaved float2 [SEQ][HD], idx d&31).
// ---------------------------------------------------------------------------
__global__ __launch_bounds__(256)
void prep(const float* __restrict__ x, const float* __restrict__ ctx,
          const float* __restrict__ Wq, const float* __restrict__ Wk,
          const float* __restrict__ Wv, const float* __restrict__ Wo,
          unsigned short* __restrict__ xb, unsigned short* __restrict__ cb,
          unsigned short* __restrict__ WqT, unsigned short* __restrict__ WkT,
          unsigned short* __restrict__ WvT, unsigned short* __restrict__ WoT,
          float2* __restrict__ cstab)
{
    __shared__ float tile[32][33];
    const int blk = blockIdx.x, t = threadIdx.x;
    if (blk < 8192) {
        const float* src = (blk < 4096) ? x : ctx;
        unsigned short* dst = (blk < 4096) ? xb : cb;
        int e = ((blk & 4095) * 256 + t) * 8;
        float4 f0 = *(const float4*)&src[e];
        float4 f1 = *(const float4*)&src[e + 4];
        uint4 o = { pk2(f0.x, f0.y), pk2(f0.z, f0.w), pk2(f1.x, f1.y), pk2(f1.z, f1.w) };
        *(uint4*)&dst[e] = o;
    } else if (blk < 12288) {
        int id2 = blk - 8192;
        const float* W; unsigned short* T;
        switch (id2 >> 10) {
            case 0:  W = Wq; T = WqT; break;
            case 1:  W = Wk; T = WkT; break;
            case 2:  W = Wv; T = WvT; break;
            default: W = Wo; T = WoT; break;
        }
        int local = id2 & 1023;
        int n0 = (local & 31) * 32, k0 = (local >> 5) * 32;
        int tx = t & 31, ty = t >> 5;
        #pragma unroll
        for (int a = 0; a < 4; a++)
            tile[ty + 8 * a][tx] = W[(size_t)(k0 + ty + 8 * a) * DIM + n0 + tx];
        __syncthreads();
        #pragma unroll
        for (int a = 0; a < 4; a++)
            T[(size_t)(n0 + ty + 8 * a) * DIM + k0 + tx] = f2bf(tile[tx][ty + 8 * a]);
    } else {
        int gid = (blk - 12288) * 256 + t;   // 0 .. SEQ*HD-1
        int d = gid & (HD - 1), s = gid >> 6;
        const float C = -0.41524101186092f;  // -2*log2(10000)/64
        float f = exp2f((float)(d & 31) * C);
        float a = (float)s * f;
        cstab[gid] = make_float2(cosf(a), sinf(a));
    }
}

// ---------------------------------------------------------------------------
// Shared GEMM main loop (round-0 verified): 128x128 tile, BK=64, glds16
// staging with XOR-swizzled LDS layout (physical 16B chunk p at row r holds
// logical chunk p^(r&7)) — fragment ds_read_b128 <=2-way bank aliasing.
// TRANSPOSED accumulate: acc = mfma(B_frag, A_frag) -> regs hold 4 consecutive n.
// NOTE (r5): VGPR floor ~112; forcing 5 blocks/CU spills. 4/CU is the max.
// ---------------------------------------------------------------------------
static __device__ __forceinline__ void gemm_main(
    const unsigned short* __restrict__ A, const unsigned short* __restrict__ Bt,
    int m0, int n0, unsigned short* As, unsigned short* Bs, floatx4 acc[4][4])
{
    const int t = threadIdx.x;
    const int w = t >> 6, l = t & 63;
    const int wm = w >> 1, wn = w & 1;
    const int lane16 = l & 15, quad = l >> 4;
    const int lr = l >> 3;
    const int gsw = ((l & 7) ^ lr) * 8;          // swizzled source col (shorts)
    const int co0 = (quad ^ (lane16 & 7)) * 8;   // fragment chunk offset, kk=0
    const int co1 = co0 ^ 32;                    // kk=1 (^4 chunks = ^32 shorts)

    #pragma unroll
    for (int mi = 0; mi < 4; mi++)
        #pragma unroll
        for (int ni = 0; ni < 4; ni++) acc[mi][ni] = (floatx4){0.f, 0.f, 0.f, 0.f};

    const unsigned short* ap = A  + (size_t)(m0 + w * 32 + lr) * DIM + gsw;
    const unsigned short* bp = Bt + (size_t)(n0 + w * 32 + lr) * DIM + gsw;

    for (int kt = 0; kt < DIM; kt += 64) {
        #pragma unroll
        for (int j = 0; j < 4; j++) {
            glds16(ap + (size_t)j * 8 * DIM + kt, &As[(w * 4 + j) * 512]);
            glds16(bp + (size_t)j * 8 * DIM + kt, &Bs[(w * 4 + j) * 512]);
        }
        __syncthreads();
        #pragma unroll
        for (int kk = 0; kk < 2; kk++) {
            const int co = kk ? co1 : co0;
            bf16x8 af[4], bfr[4];
            #pragma unroll
            for (int mi = 0; mi < 4; mi++)
                af[mi] = *(const bf16x8*)&As[(wm * 64 + mi * 16 + lane16) * 64 + co];
            #pragma unroll
            for (int ni = 0; ni < 4; ni++)
                bfr[ni] = *(const bf16x8*)&Bs[(wn * 64 + ni * 16 + lane16) * 64 + co];
            #pragma unroll
            for (int mi = 0; mi < 4; mi++)
                #pragma unroll
                for (int ni = 0; ni < 4; ni++)
                    acc[mi][ni] = __builtin_amdgcn_mfma_f32_16x16x32_bf16(bfr[ni], af[mi], acc[mi][ni], 0, 0, 0);
        }
        __syncthreads();
    }
}

// epilogue helper: mode 0 = rope split-head bf16, mode 1 = V^T bf16
static __device__ __forceinline__ void proj_epilogue(
    unsigned short* __restrict__ Out, const float2* __restrict__ cstab,
    int m0, int n0, int mode, floatx4 acc[4][4])
{
    const int t = threadIdx.x;
    const int w = t >> 6, l = t & 63;
    const int wm = w >> 1, wn = w & 1;
    const int lane16 = l & 15, quad = l >> 4;

    if (mode == 0) {
        #pragma unroll
        for (int mi = 0; mi < 4; mi++) {
            int m = m0 + wm * 64 + mi * 16 + lane16;
            int s = m & 511, b = m >> 9;
            #pragma unroll
            for (int ni = 0; ni < 4; ni++) {
                int n = n0 + wn * 64 + ni * 16 + quad * 4;
                int h = n >> 6, d0 = n & 63;
                const float4* cp = (const float4*)&cstab[s * HD + d0];
                float4 c01 = cp[0];   // cos[d0], sin[d0], cos[d0+1], sin[d0+1]
                float4 c23 = cp[1];
                floatx4 v = acc[mi][ni];
                float r0 = v[0] * c01.x - v[1] * c01.y;
                float r1 = fmaf(v[0], c01.w, v[1] * c01.z);
                float r2 = v[2] * c23.x - v[3] * c23.y;
                float r3 = fmaf(v[2], c23.w, v[3] * c23.z);
                uint2 o = { pk2(r0, r1), pk2(r2, r3) };
                *(uint2*)&Out[((size_t)(b * NH + h) * SEQ + s) * HD + d0] = o;
            }
        }
    } else {
        #pragma unroll
        for (int mi = 0; mi < 4; mi++) {
            int m = m0 + wm * 64 + mi * 16 + lane16;   // m = full d index
            #pragma unroll
            for (int ni = 0; ni < 4; ni++) {
                int n = n0 + wn * 64 + ni * 16 + quad * 4;   // flat (b*512+s)
                floatx4 v = acc[mi][ni];
                uint2 o = { pk2(v[0], v[1]), pk2(v[2], v[3]) };
                *(uint2*)&Out[((size_t)(n >> 9) * DIM + m) * SEQ + (n & 511)] = o;
            }
        }
    }
}

// ---------------------------------------------------------------------------
// K + V^T projections: 1024 blocks = 4/CU, one clean round.
// [0,512) K+rope, [512,1024) V^T. Same per-512 XCD swizzle as before.
// (Split from the old 1536-block proj_qkv so that attn/prep/out_gemm can
// surface in the rocprof top-5 — visibility round.)
// ---------------------------------------------------------------------------
__global__ __launch_bounds__(256)
void proj_kv(const unsigned short* __restrict__ cb,
             const unsigned short* __restrict__ WkT, const unsigned short* __restrict__ WvT,
             unsigned short* __restrict__ Kb, unsigned short* __restrict__ Vtb,
             const float2* __restrict__ cstab)
{
    __shared__ unsigned short As[128 * 64];
    __shared__ unsigned short Bs[128 * 64];
    const int id = blockIdx.x;
    const int local = id & 511;
    const int xcd = local & 7, seq = local >> 3;
    const unsigned short *A, *Bt; unsigned short* Out;
    int m0, n0, mode;
    if (id < 512) { A = cb;  Bt = WkT; Out = Kb;  mode = 0;
                    n0 = (seq & 7) * 128; m0 = (xcd + 8 * (seq >> 3)) * 128; }
    else          { A = WvT; Bt = cb;  Out = Vtb; mode = 1;
                    m0 = (seq & 7) * 128; n0 = (xcd + 8 * (seq >> 3)) * 128; }
    floatx4 acc[4][4];
    gemm_main(A, Bt, m0, n0, As, Bs, acc);
    proj_epilogue(Out, cstab, m0, n0, mode, acc);
}

// ---------------------------------------------------------------------------
// Q projection: 512 blocks (2/CU).
// ---------------------------------------------------------------------------
__global__ __launch_bounds__(256)
void proj_q(const unsigned short* __restrict__ xb, const unsigned short* __restrict__ WqT,
            unsigned short* __restrict__ Qb, const float2* __restrict__ cstab)
{
    __shared__ unsigned short As[128 * 64];
    __shared__ unsigned short Bs[128 * 64];
    const int id = blockIdx.x;
    const int xcd = id & 7, seq = id >> 3;
    const int n0 = (seq & 7) * 128, m0 = (xcd + 8 * (seq >> 3)) * 128;
    floatx4 acc[4][4];
    gemm_main(xb, WqT, m0, n0, As, Bs, acc);
    proj_epilogue(Qb, cstab, m0, n0, 0, acc);
}

// ---------------------------------------------------------------------------
// Output projection v2: 64x128 tile, per-wave 32x64 (acc[2][4]) -> 1024
// blocks = 4 blocks/CU (was 512 = 2/CU, half the CU capacity idle).
// Same fragment algebra / XOR swizzle, scaled. f32 out + bias.
// ---------------------------------------------------------------------------
__global__ __launch_bounds__(256)
void out_gemm(const unsigned short* __restrict__ Ab, const unsigned short* __restrict__ WoT,
              float* __restrict__ O, const float* __restrict__ bias)
{
    __shared__ unsigned short As[64 * 64];    // 8 KB
    __shared__ unsigned short Bs[128 * 64];   // 16 KB
    const int id = blockIdx.x;
    const int xcd = id & 7, seq = id >> 3;
    const int n0 = (seq & 7) * 128;                    // 8 N-tiles of 128
    const int m0 = (xcd + 8 * (seq >> 3)) * 64;        // 128 M-tiles of 64

    const int t = threadIdx.x;
    const int w = t >> 6, l = t & 63;
    const int wm = w >> 1, wn = w & 1;                 // 2M x 2N waves, 32x64 each
    const int lane16 = l & 15, quad = l >> 4;
    const int lr = l >> 3;
    const int gsw = ((l & 7) ^ lr) * 8;
    const int co0 = (quad ^ (lane16 & 7)) * 8;
    const int co1 = co0 ^ 32;

    floatx4 acc[2][4];
    #pragma unroll
    for (int mi = 0; mi < 2; mi++)
        #pragma unroll
        for (int ni = 0; ni < 4; ni++) acc[mi][ni] = (floatx4){0.f, 0.f, 0.f, 0.f};

    const unsigned short* ap = Ab  + (size_t)(m0 + w * 16 + lr) * DIM + gsw;
    const unsigned short* bp = WoT + (size_t)(n0 + w * 32 + lr) * DIM + gsw;

    for (int kt = 0; kt < DIM; kt += 64) {
        #pragma unroll
        for (int j = 0; j < 2; j++)
            glds16(ap + (size_t)j * 8 * DIM + kt, &As[(w * 2 + j) * 512]);
        #pragma unroll
        for (int j = 0; j < 4; j++)
            glds16(bp + (size_t)j * 8 * DIM + kt, &Bs[(w * 4 + j) * 512]);
        __syncthreads();
        #pragma unroll
        for (int kk = 0; kk < 2; kk++) {
            const int co = kk ? co1 : co0;
            bf16x8 af[2], bfr[4];
            #pragma unroll
            for (int mi = 0; mi < 2; mi++)
                af[mi] = *(const bf16x8*)&As[(wm * 32 + mi * 16 + lane16) * 64 + co];
            #pragma unroll
            for (int ni = 0; ni < 4; ni++)
                bfr[ni] = *(const bf16x8*)&Bs[(wn * 64 + ni * 16 + lane16) * 64 + co];
            #pragma unroll
            for (int mi = 0; mi < 2; mi++)
                #pragma unroll
                for (int ni = 0; ni < 4; ni++)
                    acc[mi][ni] = __builtin_amdgcn_mfma_f32_16x16x32_bf16(bfr[ni], af[mi], acc[mi][ni], 0, 0, 0);
        }
        __syncthreads();
    }

    #pragma unroll
    for (int ni = 0; ni < 4; ni++) {
        int n = n0 + wn * 64 + ni * 16 + quad * 4;
        float4 bv = *(const float4*)&bias[n];
        #pragma unroll
        for (int mi = 0; mi < 2; mi++) {
            int m = m0 + wm * 32 + mi * 16 + lane16;
            floatx4 v = acc[mi][ni];
            float4 o = { v[0] + bv.x, v[1] + bv.y, v[2] + bv.z, v[3] + bv.w };
            *(float4*)&O[(size_t)m * DIM + n] = o;
        }
    }
}

// ---------------------------------------------------------------------------
// Flash attention v6 (round-7 verified): single-barrier pipeline.
// Q in registers; K/V double-buffered LDS; T14 register prefetch.
// ---------------------------------------------------------------------------
__global__ __launch_bounds__(256, 4)
void attn_v4(const unsigned short* __restrict__ Q, const unsigned short* __restrict__ K,
             const unsigned short* __restrict__ Vt, unsigned short* __restrict__ Out)
{
    __shared__ unsigned short Ks[2][64][72];
    __shared__ unsigned short Vts[2][64][72];   // Vts[buf][d][kv_local]

    const int id = blockIdx.x;
    const int qi = (id >> 3) & 3;
    const int bh = (id & 7) | ((id >> 5) << 3);
    const int q0 = qi * 128;
    const int t  = threadIdx.x;
    const int w = t >> 6, l = t & 63;
    const int lane16 = l & 15, quad = l >> 4;
    const size_t base = (size_t)bh * SEQ * HD;

    // Q fragments straight to registers: row q0+st*64+w*16+lane16, col kk*32+quad*8
    bf16x8 qreg[2][2];
    #pragma unroll
    for (int st = 0; st < 2; st++)
        #pragma unroll
        for (int kk = 0; kk < 2; kk++)
            qreg[st][kk] = *(const bf16x8*)&Q[base +
                (size_t)(q0 + st * 64 + w * 16 + lane16) * HD + kk * 32 + quad * 8];

    const int sr = t >> 3, sc = (t & 7) * 8;
    const unsigned short* kp0 = K  + base + (size_t)sr * HD + sc;
    const unsigned short* kp1 = kp0 + (size_t)32 * HD;
    const unsigned short* vp0 = Vt + base + (size_t)sr * SEQ + sc;
    const unsigned short* vp1 = vp0 + (size_t)32 * SEQ;

    // T14 prologue: tile 0 K/V into registers
    uint4 kr0 = *(const uint4*)kp0;  kp0 += (size_t)64 * HD;
    uint4 kr1 = *(const uint4*)kp1;  kp1 += (size_t)64 * HD;
    uint4 vr0 = *(const uint4*)vp0;  vp0 += 64;
    uint4 vr1 = *(const uint4*)vp1;  vp1 += 64;

    floatx4 acc_o[2][4];
    float lsum[2] = {0.f, 0.f};
    #pragma unroll
    for (int st = 0; st < 2; st++)
        #pragma unroll
        for (int dt = 0; dt < 4; dt++) acc_o[st][dt] = (floatx4){0.f, 0.f, 0.f, 0.f};

    for (int it = 0; it < 8; ++it) {
        const int cb = it & 1;
        // write this tile to buffer cb; previous reader of cb (iteration it-2)
        // is separated by iteration it-1's collective barrier -> WAR-safe.
        *(uint4*)&Ks[cb][sr][sc]       = kr0;
        *(uint4*)&Ks[cb][sr + 32][sc]  = kr1;
        *(uint4*)&Vts[cb][sr][sc]      = vr0;
        *(uint4*)&Vts[cb][sr + 32][sc] = vr1;
        if (it < 7) {                          // issue next-tile loads; hide under compute
            kr0 = *(const uint4*)kp0;  kp0 += (size_t)64 * HD;
            kr1 = *(const uint4*)kp1;  kp1 += (size_t)64 * HD;
            vr0 = *(const uint4*)vp0;  vp0 += 64;
            vr1 = *(const uint4*)vp1;  vp1 += 64;
        }
        asm volatile("s_waitcnt lgkmcnt(0)" ::: "memory");   // own ds_writes drained
        __builtin_amdgcn_s_barrier();          // all stores to buf cb visible

        short4v pa[2][4];
        #pragma unroll
        for (int st = 0; st < 2; st++) {
            floatx4 sacc[4];
            #pragma unroll
            for (int c = 0; c < 4; c++) sacc[c] = (floatx4){0.f, 0.f, 0.f, 0.f};
            #pragma unroll
            for (int kk = 0; kk < 2; kk++)
                #pragma unroll
                for (int c = 0; c < 4; c++) {
                    bf16x8 kf = *(const bf16x8*)&Ks[cb][c * 16 + lane16][kk * 32 + quad * 8];
                    sacc[c] = __builtin_amdgcn_mfma_f32_16x16x32_bf16(kf, qreg[st][kk], sacc[c], 0, 0, 0);
                }
            #pragma unroll
            for (int c = 0; c < 4; c++) {
                short4v pk;
                #pragma unroll
                for (int i = 0; i < 4; i++) {
                    float pv = exp2f(sacc[c][i] * SL2E);
                    lsum[st] += pv;
                    pk[i] = (short)f2bf(pv);
                }
                pa[st][c] = pk;
            }
        }
        #pragma unroll
        for (int c = 0; c < 4; c++) {
            #pragma unroll
            for (int dt = 0; dt < 4; dt++) {
                short4v vf = *(const short4v*)&Vts[cb][dt * 16 + lane16][c * 16 + quad * 4];
                #pragma unroll
                for (int st = 0; st < 2; st++)
                    acc_o[st][dt] = __builtin_amdgcn_mfma_f32_16x16x16bf16_1k(
                        vf, pa[st][c], acc_o[st][dt], 0, 0, 0);
            }
        }
    }

    const int b = bh >> 4, h = bh & 15;
    #pragma unroll
    for (int st = 0; st < 2; st++) {
        float rs = lsum[st];
        rs += __shfl_xor(rs, 16, 64);
        rs += __shfl_xor(rs, 32, 64);
        float inv = 1.0f / rs;
        int s = q0 + st * 64 + w * 16 + lane16;
        size_t rowbase = (size_t)(b * SEQ + s) * DIM + h * HD;
        #pragma unroll
        for (int dt = 0; dt < 4; dt++) {
            floatx4 v = acc_o[st][dt];
            uint2 o = { pk2(v[0] * inv, v[1] * inv), pk2(v[2] * inv, v[3] * inv) };
            *(uint2*)&Out[rowbase + dt * 16 + quad * 4] = o;
        }
    }
}

// ---------------------------------------------------------------------------
extern "C" void kernel_launch(void* const* d_in, const int* in_sizes, int n_in,
                              void* d_out, int out_size, void* d_ws, size_t ws_size,
                              hipStream_t stream)
{
    const float* x   = (const float*)d_in[0];
    const float* ctx = (const float*)d_in[1];
    const float* Wq  = (const float*)d_in[2];
    const float* Wk  = (const float*)d_in[3];
    const float* Wv  = (const float*)d_in[4];
    const float* Wo  = (const float*)d_in[5];
    const float* bo  = (const float*)d_in[6];

    const size_t NW = (size_t)DIM * DIM;      // 1M elems
    const size_t NB = (size_t)MROWS * DIM;    // 8.4M elems

    unsigned short* x_bf   = (unsigned short*)d_ws;   // 16.8 MB (reused as Ab)
    unsigned short* ctx_bf = x_bf + NB;               // 16.8 MB
    unsigned short* WqT    = ctx_bf + NB;             // 2 MB each
    unsigned short* WkT    = WqT + NW;
    unsigned short* WvT    = WkT + NW;
    unsigned short* WoT    = WvT + NW;
    unsigned short* Kb     = WoT + NW;                // 16.8 MB
    unsigned short* Vtb    = Kb + NB;                 // 16.8 MB
    float2*         cstab  = (float2*)(Vtb + NB);     // 256 KB — total ~75.5 MB
    unsigned short* Qb     = (unsigned short*)d_out;  // scratch: d_out (33.5 MB) holds
                                                      // bf16 Q until out_gemm overwrites
    unsigned short* Ab     = x_bf;                    // alias: x_bf dead after projections

    prep<<<12416, 256, 0, stream>>>(x, ctx, Wq, Wk, Wv, Wo,
                                    x_bf, ctx_bf, WqT, WkT, WvT, WoT, cstab);

    proj_kv<<<1024, 256, 0, stream>>>(ctx_bf, WkT, WvT, Kb, Vtb, cstab);

    proj_q<<<512, 256, 0, stream>>>(x_bf, WqT, Qb, cstab);

    attn_v4<<<1024, 256, 0, stream>>>(Qb, Kb, Vtb, Ab);

    out_gemm<<<1024, 256, 0, stream>>>(Ab, WoT, (float*)d_out, bo);
}

// Round 10
// 261.297 us; speedup vs baseline: 1.0270x; 1.0270x over previous
//
#include <hip/hip_runtime.h>

#define DIM   1024
#define NH    16
#define HD    64
#define BATCH 16
#define SEQ   512
#define MROWS (BATCH*SEQ)   // 8192
#define SL2E  0.18033688011112042f   // 0.125 * log2(e)

typedef __bf16 bf16x8 __attribute__((ext_vector_type(8)));
typedef float  floatx4 __attribute__((ext_vector_type(4)));
typedef short  short4v __attribute__((ext_vector_type(4)));

static __device__ __forceinline__ unsigned short f2bf(float f) {
    union { float f; unsigned u; } v; v.f = f;
    return (unsigned short)((v.u + 0x8000u) >> 16);
}
static __device__ __forceinline__ unsigned pk2(float a, float b) {
    union { float f; unsigned u; } x, y; x.f = a; y.f = b;
    return ((x.u + 0x8000u) >> 16) | ((y.u + 0x8000u) & 0xffff0000u);
}

static __device__ __forceinline__ void glds16(const void* g, void* l) {
    __builtin_amdgcn_global_load_lds(
        (const __attribute__((address_space(1))) unsigned int*)g,
        (__attribute__((address_space(3))) unsigned int*)l, 16, 0, 0);
}

// ---------------------------------------------------------------------------
// Fused prep: [0,8192) cvt x/ctx -> bf16 ; [8192,12288) transpose 4 weights ;
// [12288,12416) RoPE cos/sin table (interleaved float2 [SEQ][HD], idx d&31).
// ---------------------------------------------------------------------------
__global__ __launch_bounds__(256)
void prep(const float* __restrict__ x, const float* __restrict__ ctx,
          const float* __restrict__ Wq, const float* __restrict__ Wk,
          const float* __restrict__ Wv, const float* __restrict__ Wo,
          unsigned short* __restrict__ xb, unsigned short* __restrict__ cb,
          unsigned short* __restrict__ WqT, unsigned short* __restrict__ WkT,
          unsigned short* __restrict__ WvT, unsigned short* __restrict__ WoT,
          float2* __restrict__ cstab)
{
    __shared__ float tile[32][33];
    const int blk = blockIdx.x, t = threadIdx.x;
    if (blk < 8192) {
        const float* src = (blk < 4096) ? x : ctx;
        unsigned short* dst = (blk < 4096) ? xb : cb;
        int e = ((blk & 4095) * 256 + t) * 8;
        float4 f0 = *(const float4*)&src[e];
        float4 f1 = *(const float4*)&src[e + 4];
        uint4 o = { pk2(f0.x, f0.y), pk2(f0.z, f0.w), pk2(f1.x, f1.y), pk2(f1.z, f1.w) };
        *(uint4*)&dst[e] = o;
    } else if (blk < 12288) {
        int id2 = blk - 8192;
        const float* W; unsigned short* T;
        switch (id2 >> 10) {
            case 0:  W = Wq; T = WqT; break;
            case 1:  W = Wk; T = WkT; break;
            case 2:  W = Wv; T = WvT; break;
            default: W = Wo; T = WoT; break;
        }
        int local = id2 & 1023;
        int n0 = (local & 31) * 32, k0 = (local >> 5) * 32;
        int tx = t & 31, ty = t >> 5;
        #pragma unroll
        for (int a = 0; a < 4; a++)
            tile[ty + 8 * a][tx] = W[(size_t)(k0 + ty + 8 * a) * DIM + n0 + tx];
        __syncthreads();
        #pragma unroll
        for (int a = 0; a < 4; a++)
            T[(size_t)(n0 + ty + 8 * a) * DIM + k0 + tx] = f2bf(tile[tx][ty + 8 * a]);
    } else {
        int gid = (blk - 12288) * 256 + t;   // 0 .. SEQ*HD-1
        int d = gid & (HD - 1), s = gid >> 6;
        const float C = -0.41524101186092f;  // -2*log2(10000)/64
        float f = exp2f((float)(d & 31) * C);
        float a = (float)s * f;
        cstab[gid] = make_float2(cosf(a), sinf(a));
    }
}

// ---------------------------------------------------------------------------
// Shared GEMM main loop (round-0 verified): 128x128 tile, BK=64, glds16
// staging with XOR-swizzled LDS layout (physical 16B chunk p at row r holds
// logical chunk p^(r&7)) — fragment ds_read_b128 <=2-way bank aliasing.
// TRANSPOSED accumulate: acc = mfma(B_frag, A_frag) -> regs hold 4 consecutive n.
// NOTE (r5): VGPR floor ~112; forcing 5 blocks/CU spills. 4/CU is the max.
// NOTE (r8): fused 1536-block version beats K/V+Q split by ~13 us (occupancy
// beats raggedness at this shape).
// ---------------------------------------------------------------------------
static __device__ __forceinline__ void gemm_main(
    const unsigned short* __restrict__ A, const unsigned short* __restrict__ Bt,
    int m0, int n0, unsigned short* As, unsigned short* Bs, floatx4 acc[4][4])
{
    const int t = threadIdx.x;
    const int w = t >> 6, l = t & 63;
    const int wm = w >> 1, wn = w & 1;
    const int lane16 = l & 15, quad = l >> 4;
    const int lr = l >> 3;
    const int gsw = ((l & 7) ^ lr) * 8;          // swizzled source col (shorts)
    const int co0 = (quad ^ (lane16 & 7)) * 8;   // fragment chunk offset, kk=0
    const int co1 = co0 ^ 32;                    // kk=1 (^4 chunks = ^32 shorts)

    #pragma unroll
    for (int mi = 0; mi < 4; mi++)
        #pragma unroll
        for (int ni = 0; ni < 4; ni++) acc[mi][ni] = (floatx4){0.f, 0.f, 0.f, 0.f};

    const unsigned short* ap = A  + (size_t)(m0 + w * 32 + lr) * DIM + gsw;
    const unsigned short* bp = Bt + (size_t)(n0 + w * 32 + lr) * DIM + gsw;

    for (int kt = 0; kt < DIM; kt += 64) {
        #pragma unroll
        for (int j = 0; j < 4; j++) {
            glds16(ap + (size_t)j * 8 * DIM + kt, &As[(w * 4 + j) * 512]);
            glds16(bp + (size_t)j * 8 * DIM + kt, &Bs[(w * 4 + j) * 512]);
        }
        __syncthreads();
        #pragma unroll
        for (int kk = 0; kk < 2; kk++) {
            const int co = kk ? co1 : co0;
            bf16x8 af[4], bfr[4];
            #pragma unroll
            for (int mi = 0; mi < 4; mi++)
                af[mi] = *(const bf16x8*)&As[(wm * 64 + mi * 16 + lane16) * 64 + co];
            #pragma unroll
            for (int ni = 0; ni < 4; ni++)
                bfr[ni] = *(const bf16x8*)&Bs[(wn * 64 + ni * 16 + lane16) * 64 + co];
            #pragma unroll
            for (int mi = 0; mi < 4; mi++)
                #pragma unroll
                for (int ni = 0; ni < 4; ni++)
                    acc[mi][ni] = __builtin_amdgcn_mfma_f32_16x16x32_bf16(bfr[ni], af[mi], acc[mi][ni], 0, 0, 0);
        }
        __syncthreads();
    }
}

// epilogue helper: mode 0 = rope split-head bf16, mode 1 = V^T bf16
static __device__ __forceinline__ void proj_epilogue(
    unsigned short* __restrict__ Out, const float2* __restrict__ cstab,
    int m0, int n0, int mode, floatx4 acc[4][4])
{
    const int t = threadIdx.x;
    const int w = t >> 6, l = t & 63;
    const int wm = w >> 1, wn = w & 1;
    const int lane16 = l & 15, quad = l >> 4;

    if (mode == 0) {
        #pragma unroll
        for (int mi = 0; mi < 4; mi++) {
            int m = m0 + wm * 64 + mi * 16 + lane16;
            int s = m & 511, b = m >> 9;
            #pragma unroll
            for (int ni = 0; ni < 4; ni++) {
                int n = n0 + wn * 64 + ni * 16 + quad * 4;
                int h = n >> 6, d0 = n & 63;
                const float4* cp = (const float4*)&cstab[s * HD + d0];
                float4 c01 = cp[0];   // cos[d0], sin[d0], cos[d0+1], sin[d0+1]
                float4 c23 = cp[1];
                floatx4 v = acc[mi][ni];
                float r0 = v[0] * c01.x - v[1] * c01.y;
                float r1 = fmaf(v[0], c01.w, v[1] * c01.z);
                float r2 = v[2] * c23.x - v[3] * c23.y;
                float r3 = fmaf(v[2], c23.w, v[3] * c23.z);
                uint2 o = { pk2(r0, r1), pk2(r2, r3) };
                *(uint2*)&Out[((size_t)(b * NH + h) * SEQ + s) * HD + d0] = o;
            }
        }
    } else {
        #pragma unroll
        for (int mi = 0; mi < 4; mi++) {
            int m = m0 + wm * 64 + mi * 16 + lane16;   // m = full d index
            #pragma unroll
            for (int ni = 0; ni < 4; ni++) {
                int n = n0 + wn * 64 + ni * 16 + quad * 4;   // flat (b*512+s)
                floatx4 v = acc[mi][ni];
                uint2 o = { pk2(v[0], v[1]), pk2(v[2], v[3]) };
                *(uint2*)&Out[((size_t)(n >> 9) * DIM + m) * SEQ + (n & 511)] = o;
            }
        }
    }
}

// ---------------------------------------------------------------------------
// All three projections in one launch, 1536 blocks:
// [0,512) K+rope, [512,1024) V^T, [1024,1536) Q+rope.
// Per-512 grid swizzle: the 8 blocks sharing an A-strip get id = same (mod 8)
// (same XCD under round-robin) and adjacent dispatch order.
// ---------------------------------------------------------------------------
__global__ __launch_bounds__(256)
void proj_qkv(const unsigned short* __restrict__ xb, const unsigned short* __restrict__ cb,
              const unsigned short* __restrict__ WqT, const unsigned short* __restrict__ WkT,
              const unsigned short* __restrict__ WvT,
              unsigned short* __restrict__ Qb, unsigned short* __restrict__ Kb,
              unsigned short* __restrict__ Vtb, const float2* __restrict__ cstab)
{
    __shared__ unsigned short As[128 * 64];
    __shared__ unsigned short Bs[128 * 64];
    const int id = blockIdx.x;
    const int seg = id >> 9, local = id & 511;
    const int xcd = local & 7, seq = local >> 3;
    const unsigned short *A, *Bt; unsigned short* Out;
    int m0, n0, mode;
    if (seg == 0)      { A = cb;  Bt = WkT; Out = Kb;  mode = 0;
                         n0 = (seq & 7) * 128; m0 = (xcd + 8 * (seq >> 3)) * 128; }
    else if (seg == 1) { A = WvT; Bt = cb;  Out = Vtb; mode = 1;
                         m0 = (seq & 7) * 128; n0 = (xcd + 8 * (seq >> 3)) * 128; }
    else               { A = xb;  Bt = WqT; Out = Qb;  mode = 0;
                         n0 = (seq & 7) * 128; m0 = (xcd + 8 * (seq >> 3)) * 128; }
    floatx4 acc[4][4];
    gemm_main(A, Bt, m0, n0, As, Bs, acc);
    proj_epilogue(Out, cstab, m0, n0, mode, acc);
}

// ---------------------------------------------------------------------------
// Output projection: f32 out + bias, float4 stores; same grid swizzle.
// ---------------------------------------------------------------------------
__global__ __launch_bounds__(256)
void out_gemm(const unsigned short* __restrict__ Ab, const unsigned short* __restrict__ WoT,
              float* __restrict__ O, const float* __restrict__ bias)
{
    __shared__ unsigned short As[128 * 64];
    __shared__ unsigned short Bs[128 * 64];
    const int id = blockIdx.x;
    const int xcd = id & 7, seq = id >> 3;
    const int n0 = (seq & 7) * 128, m0 = (xcd + 8 * (seq >> 3)) * 128;
    floatx4 acc[4][4];
    gemm_main(Ab, WoT, m0, n0, As, Bs, acc);

    const int t = threadIdx.x;
    const int w = t >> 6, l = t & 63;
    const int wm = w >> 1, wn = w & 1;
    const int lane16 = l & 15, quad = l >> 4;
    #pragma unroll
    for (int ni = 0; ni < 4; ni++) {
        int n = n0 + wn * 64 + ni * 16 + quad * 4;
        float4 bv = *(const float4*)&bias[n];
        #pragma unroll
        for (int mi = 0; mi < 4; mi++) {
            int m = m0 + wm * 64 + mi * 16 + lane16;
            floatx4 v = acc[mi][ni];
            float4 o = { v[0] + bv.x, v[1] + bv.y, v[2] + bv.z, v[3] + bv.w };
            *(float4*)&O[(size_t)m * DIM + n] = o;
        }
    }
}

// ---------------------------------------------------------------------------
// Flash attention v7: v6 single-barrier pipeline + kf cache restored.
//  - Q fragments in registers; K/V double-buffered LDS; T14 reg prefetch.
//  - kf[2][4] hoisted OUT of the st loop (kf is st-invariant): 8 ds_read_b128
//    per iter instead of 16 -> LDS read traffic 24KB -> 16KB per wave-iter.
// ---------------------------------------------------------------------------
__global__ __launch_bounds__(256, 4)
void attn_v4(const unsigned short* __restrict__ Q, const unsigned short* __restrict__ K,
             const unsigned short* __restrict__ Vt, unsigned short* __restrict__ Out)
{
    __shared__ unsigned short Ks[2][64][72];
    __shared__ unsigned short Vts[2][64][72];   // Vts[buf][d][kv_local]

    const int id = blockIdx.x;
    const int qi = (id >> 3) & 3;
    const int bh = (id & 7) | ((id >> 5) << 3);
    const int q0 = qi * 128;
    const int t  = threadIdx.x;
    const int w = t >> 6, l = t & 63;
    const int lane16 = l & 15, quad = l >> 4;
    const size_t base = (size_t)bh * SEQ * HD;

    // Q fragments straight to registers: row q0+st*64+w*16+lane16, col kk*32+quad*8
    bf16x8 qreg[2][2];
    #pragma unroll
    for (int st = 0; st < 2; st++)
        #pragma unroll
        for (int kk = 0; kk < 2; kk++)
            qreg[st][kk] = *(const bf16x8*)&Q[base +
                (size_t)(q0 + st * 64 + w * 16 + lane16) * HD + kk * 32 + quad * 8];

    const int sr = t >> 3, sc = (t & 7) * 8;
    const unsigned short* kp0 = K  + base + (size_t)sr * HD + sc;
    const unsigned short* kp1 = kp0 + (size_t)32 * HD;
    const unsigned short* vp0 = Vt + base + (size_t)sr * SEQ + sc;
    const unsigned short* vp1 = vp0 + (size_t)32 * SEQ;

    // T14 prologue: tile 0 K/V into registers
    uint4 kr0 = *(const uint4*)kp0;  kp0 += (size_t)64 * HD;
    uint4 kr1 = *(const uint4*)kp1;  kp1 += (size_t)64 * HD;
    uint4 vr0 = *(const uint4*)vp0;  vp0 += 64;
    uint4 vr1 = *(const uint4*)vp1;  vp1 += 64;

    floatx4 acc_o[2][4];
    float lsum[2] = {0.f, 0.f};
    #pragma unroll
    for (int st = 0; st < 2; st++)
        #pragma unroll
        for (int dt = 0; dt < 4; dt++) acc_o[st][dt] = (floatx4){0.f, 0.f, 0.f, 0.f};

    for (int it = 0; it < 8; ++it) {
        const int cb = it & 1;
        // write this tile to buffer cb; previous reader of cb (iteration it-2)
        // is separated by iteration it-1's collective barrier -> WAR-safe.
        *(uint4*)&Ks[cb][sr][sc]       = kr0;
        *(uint4*)&Ks[cb][sr + 32][sc]  = kr1;
        *(uint4*)&Vts[cb][sr][sc]      = vr0;
        *(uint4*)&Vts[cb][sr + 32][sc] = vr1;
        if (it < 7) {                          // issue next-tile loads; hide under compute
            kr0 = *(const uint4*)kp0;  kp0 += (size_t)64 * HD;
            kr1 = *(const uint4*)kp1;  kp1 += (size_t)64 * HD;
            vr0 = *(const uint4*)vp0;  vp0 += 64;
            vr1 = *(const uint4*)vp1;  vp1 += 64;
        }
        asm volatile("s_waitcnt lgkmcnt(0)" ::: "memory");   // own ds_writes drained
        __builtin_amdgcn_s_barrier();          // all stores to buf cb visible

        // kf is st-invariant: load once per iteration (8 x ds_read_b128)
        bf16x8 kf[2][4];
        #pragma unroll
        for (int kk = 0; kk < 2; kk++)
            #pragma unroll
            for (int c = 0; c < 4; c++)
                kf[kk][c] = *(const bf16x8*)&Ks[cb][c * 16 + lane16][kk * 32 + quad * 8];

        short4v pa[2][4];
        #pragma unroll
        for (int st = 0; st < 2; st++) {
            floatx4 sacc[4];
            #pragma unroll
            for (int c = 0; c < 4; c++) sacc[c] = (floatx4){0.f, 0.f, 0.f, 0.f};
            #pragma unroll
            for (int kk = 0; kk < 2; kk++)
                #pragma unroll
                for (int c = 0; c < 4; c++)
                    sacc[c] = __builtin_amdgcn_mfma_f32_16x16x32_bf16(kf[kk][c], qreg[st][kk], sacc[c], 0, 0, 0);
            #pragma unroll
            for (int c = 0; c < 4; c++) {
                short4v pk;
                #pragma unroll
                for (int i = 0; i < 4; i++) {
                    float pv = exp2f(sacc[c][i] * SL2E);
                    lsum[st] += pv;
                    pk[i] = (short)f2bf(pv);
                }
                pa[st][c] = pk;
            }
        }
        #pragma unroll
        for (int c = 0; c < 4; c++) {
            #pragma unroll
            for (int dt = 0; dt < 4; dt++) {
                short4v vf = *(const short4v*)&Vts[cb][dt * 16 + lane16][c * 16 + quad * 4];
                #pragma unroll
                for (int st = 0; st < 2; st++)
                    acc_o[st][dt] = __builtin_amdgcn_mfma_f32_16x16x16bf16_1k(
                        vf, pa[st][c], acc_o[st][dt], 0, 0, 0);
            }
        }
    }

    const int b = bh >> 4, h = bh & 15;
    #pragma unroll
    for (int st = 0; st < 2; st++) {
        float rs = lsum[st];
        rs += __shfl_xor(rs, 16, 64);
        rs += __shfl_xor(rs, 32, 64);
        float inv = 1.0f / rs;
        int s = q0 + st * 64 + w * 16 + lane16;
        size_t rowbase = (size_t)(b * SEQ + s) * DIM + h * HD;
        #pragma unroll
        for (int dt = 0; dt < 4; dt++) {
            floatx4 v = acc_o[st][dt];
            uint2 o = { pk2(v[0] * inv, v[1] * inv), pk2(v[2] * inv, v[3] * inv) };
            *(uint2*)&Out[rowbase + dt * 16 + quad * 4] = o;
        }
    }
}

// ---------------------------------------------------------------------------
extern "C" void kernel_launch(void* const* d_in, const int* in_sizes, int n_in,
                              void* d_out, int out_size, void* d_ws, size_t ws_size,
                              hipStream_t stream)
{
    const float* x   = (const float*)d_in[0];
    const float* ctx = (const float*)d_in[1];
    const float* Wq  = (const float*)d_in[2];
    const float* Wk  = (const float*)d_in[3];
    const float* Wv  = (const float*)d_in[4];
    const float* Wo  = (const float*)d_in[5];
    const float* bo  = (const float*)d_in[6];

    const size_t NW = (size_t)DIM * DIM;      // 1M elems
    const size_t NB = (size_t)MROWS * DIM;    // 8.4M elems

    unsigned short* x_bf   = (unsigned short*)d_ws;   // 16.8 MB (reused as Ab)
    unsigned short* ctx_bf = x_bf + NB;               // 16.8 MB
    unsigned short* WqT    = ctx_bf + NB;             // 2 MB each
    unsigned short* WkT    = WqT + NW;
    unsigned short* WvT    = WkT + NW;
    unsigned short* WoT    = WvT + NW;
    unsigned short* Kb     = WoT + NW;                // 16.8 MB
    unsigned short* Vtb    = Kb + NB;                 // 16.8 MB
    float2*         cstab  = (float2*)(Vtb + NB);     // 256 KB — total ~75.5 MB
    unsigned short* Qb     = (unsigned short*)d_out;  // scratch: d_out (33.5 MB) holds
                                                      // bf16 Q until out_gemm overwrites
    unsigned short* Ab     = x_bf;                    // alias: x_bf dead after proj_qkv

    prep<<<12416, 256, 0, stream>>>(x, ctx, Wq, Wk, Wv, Wo,
                                    x_bf, ctx_bf, WqT, WkT, WvT, WoT, cstab);

    proj_qkv<<<1536, 256, 0, stream>>>(x_bf, ctx_bf, WqT, WkT, WvT,
                                       Qb, Kb, Vtb, cstab);

    attn_v4<<<1024, 256, 0, stream>>>(Qb, Kb, Vtb, Ab);

    out_gemm<<<512, 256, 0, stream>>>(Ab, WoT, (float*)d_out, bo);
}

// Round 11
// 256.570 us; speedup vs baseline: 1.0459x; 1.0184x over previous
//
#include <hip/hip_runtime.h>

#define DIM   1024
#define NH    16
#define HD    64
#define BATCH 16
#define SEQ   512
#define MROWS (BATCH*SEQ)   // 8192
#define SL2E  0.18033688011112042f   // 0.125 * log2(e)

typedef __bf16 bf16x8 __attribute__((ext_vector_type(8)));
typedef float  floatx4 __attribute__((ext_vector_type(4)));
typedef short  short4v __attribute__((ext_vector_type(4)));

static __device__ __forceinline__ unsigned short f2bf(float f) {
    union { float f; unsigned u; } v; v.f = f;
    return (unsigned short)((v.u + 0x8000u) >> 16);
}
static __device__ __forceinline__ unsigned pk2(float a, float b) {
    union { float f; unsigned u; } x, y; x.f = a; y.f = b;
    return ((x.u + 0x8000u) >> 16) | ((y.u + 0x8000u) & 0xffff0000u);
}

static __device__ __forceinline__ void glds16(const void* g, void* l) {
    __builtin_amdgcn_global_load_lds(
        (const __attribute__((address_space(1))) unsigned int*)g,
        (__attribute__((address_space(3))) unsigned int*)l, 16, 0, 0);
}

// ---------------------------------------------------------------------------
// Fused prep: [0,8192) cvt x/ctx -> bf16 ; [8192,12288) transpose 4 weights ;
// [12288,12416) RoPE cos/sin table (interleaved float2 [SEQ][HD], idx d&31).
// ---------------------------------------------------------------------------
__global__ __launch_bounds__(256)
void prep(const float* __restrict__ x, const float* __restrict__ ctx,
          const float* __restrict__ Wq, const float* __restrict__ Wk,
          const float* __restrict__ Wv, const float* __restrict__ Wo,
          unsigned short* __restrict__ xb, unsigned short* __restrict__ cb,
          unsigned short* __restrict__ WqT, unsigned short* __restrict__ WkT,
          unsigned short* __restrict__ WvT, unsigned short* __restrict__ WoT,
          float2* __restrict__ cstab)
{
    __shared__ float tile[32][33];
    const int blk = blockIdx.x, t = threadIdx.x;
    if (blk < 8192) {
        const float* src = (blk < 4096) ? x : ctx;
        unsigned short* dst = (blk < 4096) ? xb : cb;
        int e = ((blk & 4095) * 256 + t) * 8;
        float4 f0 = *(const float4*)&src[e];
        float4 f1 = *(const float4*)&src[e + 4];
        uint4 o = { pk2(f0.x, f0.y), pk2(f0.z, f0.w), pk2(f1.x, f1.y), pk2(f1.z, f1.w) };
        *(uint4*)&dst[e] = o;
    } else if (blk < 12288) {
        int id2 = blk - 8192;
        const float* W; unsigned short* T;
        switch (id2 >> 10) {
            case 0:  W = Wq; T = WqT; break;
            case 1:  W = Wk; T = WkT; break;
            case 2:  W = Wv; T = WvT; break;
            default: W = Wo; T = WoT; break;
        }
        int local = id2 & 1023;
        int n0 = (local & 31) * 32, k0 = (local >> 5) * 32;
        int tx = t & 31, ty = t >> 5;
        #pragma unroll
        for (int a = 0; a < 4; a++)
            tile[ty + 8 * a][tx] = W[(size_t)(k0 + ty + 8 * a) * DIM + n0 + tx];
        __syncthreads();
        #pragma unroll
        for (int a = 0; a < 4; a++)
            T[(size_t)(n0 + ty + 8 * a) * DIM + k0 + tx] = f2bf(tile[tx][ty + 8 * a]);
    } else {
        int gid = (blk - 12288) * 256 + t;   // 0 .. SEQ*HD-1
        int d = gid & (HD - 1), s = gid >> 6;
        const float C = -0.41524101186092f;  // -2*log2(10000)/64
        float f = exp2f((float)(d & 31) * C);
        float a = (float)s * f;
        cstab[gid] = make_float2(cosf(a), sinf(a));
    }
}

// ---------------------------------------------------------------------------
// Shared GEMM main loop (round-0 verified): 128x128 tile, BK=64, glds16
// staging with XOR-swizzled LDS layout (physical 16B chunk p at row r holds
// logical chunk p^(r&7)) — fragment ds_read_b128 <=2-way bank aliasing.
// TRANSPOSED accumulate: acc = mfma(B_frag, A_frag) -> regs hold 4 consecutive n.
// NOTE (r5): VGPR floor ~112; forcing 5 blocks/CU spills. 4/CU is the max.
// NOTE (r8): fused 1536-block version beats K/V+Q split by ~13 us.
// NOTE (r10): attn kf-hoist was null-to-negative (overlap-saturated) — v6 kept.
// ---------------------------------------------------------------------------
static __device__ __forceinline__ void gemm_main(
    const unsigned short* __restrict__ A, const unsigned short* __restrict__ Bt,
    int m0, int n0, unsigned short* As, unsigned short* Bs, floatx4 acc[4][4])
{
    const int t = threadIdx.x;
    const int w = t >> 6, l = t & 63;
    const int wm = w >> 1, wn = w & 1;
    const int lane16 = l & 15, quad = l >> 4;
    const int lr = l >> 3;
    const int gsw = ((l & 7) ^ lr) * 8;          // swizzled source col (shorts)
    const int co0 = (quad ^ (lane16 & 7)) * 8;   // fragment chunk offset, kk=0
    const int co1 = co0 ^ 32;                    // kk=1 (^4 chunks = ^32 shorts)

    #pragma unroll
    for (int mi = 0; mi < 4; mi++)
        #pragma unroll
        for (int ni = 0; ni < 4; ni++) acc[mi][ni] = (floatx4){0.f, 0.f, 0.f, 0.f};

    const unsigned short* ap = A  + (size_t)(m0 + w * 32 + lr) * DIM + gsw;
    const unsigned short* bp = Bt + (size_t)(n0 + w * 32 + lr) * DIM + gsw;

    for (int kt = 0; kt < DIM; kt += 64) {
        #pragma unroll
        for (int j = 0; j < 4; j++) {
            glds16(ap + (size_t)j * 8 * DIM + kt, &As[(w * 4 + j) * 512]);
            glds16(bp + (size_t)j * 8 * DIM + kt, &Bs[(w * 4 + j) * 512]);
        }
        __syncthreads();
        #pragma unroll
        for (int kk = 0; kk < 2; kk++) {
            const int co = kk ? co1 : co0;
            bf16x8 af[4], bfr[4];
            #pragma unroll
            for (int mi = 0; mi < 4; mi++)
                af[mi] = *(const bf16x8*)&As[(wm * 64 + mi * 16 + lane16) * 64 + co];
            #pragma unroll
            for (int ni = 0; ni < 4; ni++)
                bfr[ni] = *(const bf16x8*)&Bs[(wn * 64 + ni * 16 + lane16) * 64 + co];
            #pragma unroll
            for (int mi = 0; mi < 4; mi++)
                #pragma unroll
                for (int ni = 0; ni < 4; ni++)
                    acc[mi][ni] = __builtin_amdgcn_mfma_f32_16x16x32_bf16(bfr[ni], af[mi], acc[mi][ni], 0, 0, 0);
        }
        __syncthreads();
    }
}

// epilogue helper: mode 0 = rope split-head bf16, mode 1 = V^T bf16
static __device__ __forceinline__ void proj_epilogue(
    unsigned short* __restrict__ Out, const float2* __restrict__ cstab,
    int m0, int n0, int mode, floatx4 acc[4][4])
{
    const int t = threadIdx.x;
    const int w = t >> 6, l = t & 63;
    const int wm = w >> 1, wn = w & 1;
    const int lane16 = l & 15, quad = l >> 4;

    if (mode == 0) {
        #pragma unroll
        for (int mi = 0; mi < 4; mi++) {
            int m = m0 + wm * 64 + mi * 16 + lane16;
            int s = m & 511, b = m >> 9;
            #pragma unroll
            for (int ni = 0; ni < 4; ni++) {
                int n = n0 + wn * 64 + ni * 16 + quad * 4;
                int h = n >> 6, d0 = n & 63;
                const float4* cp = (const float4*)&cstab[s * HD + d0];
                float4 c01 = cp[0];   // cos[d0], sin[d0], cos[d0+1], sin[d0+1]
                float4 c23 = cp[1];
                floatx4 v = acc[mi][ni];
                float r0 = v[0] * c01.x - v[1] * c01.y;
                float r1 = fmaf(v[0], c01.w, v[1] * c01.z);
                float r2 = v[2] * c23.x - v[3] * c23.y;
                float r3 = fmaf(v[2], c23.w, v[3] * c23.z);
                uint2 o = { pk2(r0, r1), pk2(r2, r3) };
                *(uint2*)&Out[((size_t)(b * NH + h) * SEQ + s) * HD + d0] = o;
            }
        }
    } else {
        #pragma unroll
        for (int mi = 0; mi < 4; mi++) {
            int m = m0 + wm * 64 + mi * 16 + lane16;   // m = full d index
            #pragma unroll
            for (int ni = 0; ni < 4; ni++) {
                int n = n0 + wn * 64 + ni * 16 + quad * 4;   // flat (b*512+s)
                floatx4 v = acc[mi][ni];
                uint2 o = { pk2(v[0], v[1]), pk2(v[2], v[3]) };
                *(uint2*)&Out[((size_t)(n >> 9) * DIM + m) * SEQ + (n & 511)] = o;
            }
        }
    }
}

// ---------------------------------------------------------------------------
// All three projections in one launch, 1536 blocks:
// [0,512) K+rope, [512,1024) V^T, [1024,1536) Q+rope.
// Per-512 grid swizzle: the 8 blocks sharing an A-strip get id = same (mod 8)
// (same XCD under round-robin) and adjacent dispatch order.
// ---------------------------------------------------------------------------
__global__ __launch_bounds__(256)
void proj_qkv(const unsigned short* __restrict__ xb, const unsigned short* __restrict__ cb,
              const unsigned short* __restrict__ WqT, const unsigned short* __restrict__ WkT,
              const unsigned short* __restrict__ WvT,
              unsigned short* __restrict__ Qb, unsigned short* __restrict__ Kb,
              unsigned short* __restrict__ Vtb, const float2* __restrict__ cstab)
{
    __shared__ unsigned short As[128 * 64];
    __shared__ unsigned short Bs[128 * 64];
    const int id = blockIdx.x;
    const int seg = id >> 9, local = id & 511;
    const int xcd = local & 7, seq = local >> 3;
    const unsigned short *A, *Bt; unsigned short* Out;
    int m0, n0, mode;
    if (seg == 0)      { A = cb;  Bt = WkT; Out = Kb;  mode = 0;
                         n0 = (seq & 7) * 128; m0 = (xcd + 8 * (seq >> 3)) * 128; }
    else if (seg == 1) { A = WvT; Bt = cb;  Out = Vtb; mode = 1;
                         m0 = (seq & 7) * 128; n0 = (xcd + 8 * (seq >> 3)) * 128; }
    else               { A = xb;  Bt = WqT; Out = Qb;  mode = 0;
                         n0 = (seq & 7) * 128; m0 = (xcd + 8 * (seq >> 3)) * 128; }
    floatx4 acc[4][4];
    gemm_main(A, Bt, m0, n0, As, Bs, acc);
    proj_epilogue(Out, cstab, m0, n0, mode, acc);
}

// ---------------------------------------------------------------------------
// Output projection v3: same 128x128 tile / swizzle algebra, but 512 THREADS
// (8 waves, 4M x 2N, per-wave 32x64, acc[2][4]).
// Rationale: grid is fixed at 512 tiles; at 256 threads that is 2 blocks/CU =
// 8 waves/CU (half capacity idle). 512 threads -> 512 blocks all resident at
// 2/CU = 16 waves/CU, doubling TLP that fills barrier-drain stalls.
// VGPR ~90 (acc 32 + frags 24 + addr), LDS 32 KB.
// ---------------------------------------------------------------------------
__global__ __launch_bounds__(512)
void out_gemm(const unsigned short* __restrict__ Ab, const unsigned short* __restrict__ WoT,
              float* __restrict__ O, const float* __restrict__ bias)
{
    __shared__ unsigned short As[128 * 64];
    __shared__ unsigned short Bs[128 * 64];
    const int id = blockIdx.x;
    const int xcd = id & 7, seq = id >> 3;
    const int n0 = (seq & 7) * 128, m0 = (xcd + 8 * (seq >> 3)) * 128;

    const int t = threadIdx.x;
    const int w = t >> 6, l = t & 63;          // 8 waves
    const int wm = w >> 1, wn = w & 1;         // 4M x 2N, per-wave 32x64
    const int lane16 = l & 15, quad = l >> 4;
    const int lr = l >> 3;
    const int gsw = ((l & 7) ^ lr) * 8;
    const int co0 = (quad ^ (lane16 & 7)) * 8;
    const int co1 = co0 ^ 32;

    floatx4 acc[2][4];
    #pragma unroll
    for (int mi = 0; mi < 2; mi++)
        #pragma unroll
        for (int ni = 0; ni < 4; ni++) acc[mi][ni] = (floatx4){0.f, 0.f, 0.f, 0.f};

    // wave w stages A rows w*16+j*8+lr and B rows w*16+j*8+lr (j=0,1)
    const unsigned short* ap = Ab  + (size_t)(m0 + w * 16 + lr) * DIM + gsw;
    const unsigned short* bp = WoT + (size_t)(n0 + w * 16 + lr) * DIM + gsw;

    for (int kt = 0; kt < DIM; kt += 64) {
        #pragma unroll
        for (int j = 0; j < 2; j++) {
            glds16(ap + (size_t)j * 8 * DIM + kt, &As[(w * 2 + j) * 512]);
            glds16(bp + (size_t)j * 8 * DIM + kt, &Bs[(w * 2 + j) * 512]);
        }
        __syncthreads();
        #pragma unroll
        for (int kk = 0; kk < 2; kk++) {
            const int co = kk ? co1 : co0;
            bf16x8 af[2], bfr[4];
            #pragma unroll
            for (int mi = 0; mi < 2; mi++)
                af[mi] = *(const bf16x8*)&As[(wm * 32 + mi * 16 + lane16) * 64 + co];
            #pragma unroll
            for (int ni = 0; ni < 4; ni++)
                bfr[ni] = *(const bf16x8*)&Bs[(wn * 64 + ni * 16 + lane16) * 64 + co];
            #pragma unroll
            for (int mi = 0; mi < 2; mi++)
                #pragma unroll
                for (int ni = 0; ni < 4; ni++)
                    acc[mi][ni] = __builtin_amdgcn_mfma_f32_16x16x32_bf16(bfr[ni], af[mi], acc[mi][ni], 0, 0, 0);
        }
        __syncthreads();
    }

    #pragma unroll
    for (int ni = 0; ni < 4; ni++) {
        int n = n0 + wn * 64 + ni * 16 + quad * 4;
        float4 bv = *(const float4*)&bias[n];
        #pragma unroll
        for (int mi = 0; mi < 2; mi++) {
            int m = m0 + wm * 32 + mi * 16 + lane16;
            floatx4 v = acc[mi][ni];
            float4 o = { v[0] + bv.x, v[1] + bv.y, v[2] + bv.z, v[3] + bv.w };
            *(float4*)&O[(size_t)m * DIM + n] = o;
        }
    }
}

// ---------------------------------------------------------------------------
// Flash attention v6 (round-7 verified, 257.6 us build): single-barrier
// pipeline. Q in registers; K/V double-buffered LDS; T14 register prefetch.
// kf read inline per st (r10: hoisting it was null-to-negative).
// ---------------------------------------------------------------------------
__global__ __launch_bounds__(256, 4)
void attn_v4(const unsigned short* __restrict__ Q, const unsigned short* __restrict__ K,
             const unsigned short* __restrict__ Vt, unsigned short* __restrict__ Out)
{
    __shared__ unsigned short Ks[2][64][72];
    __shared__ unsigned short Vts[2][64][72];   // Vts[buf][d][kv_local]

    const int id = blockIdx.x;
    const int qi = (id >> 3) & 3;
    const int bh = (id & 7) | ((id >> 5) << 3);
    const int q0 = qi * 128;
    const int t  = threadIdx.x;
    const int w = t >> 6, l = t & 63;
    const int lane16 = l & 15, quad = l >> 4;
    const size_t base = (size_t)bh * SEQ * HD;

    // Q fragments straight to registers: row q0+st*64+w*16+lane16, col kk*32+quad*8
    bf16x8 qreg[2][2];
    #pragma unroll
    for (int st = 0; st < 2; st++)
        #pragma unroll
        for (int kk = 0; kk < 2; kk++)
            qreg[st][kk] = *(const bf16x8*)&Q[base +
                (size_t)(q0 + st * 64 + w * 16 + lane16) * HD + kk * 32 + quad * 8];

    const int sr = t >> 3, sc = (t & 7) * 8;
    const unsigned short* kp0 = K  + base + (size_t)sr * HD + sc;
    const unsigned short* kp1 = kp0 + (size_t)32 * HD;
    const unsigned short* vp0 = Vt + base + (size_t)sr * SEQ + sc;
    const unsigned short* vp1 = vp0 + (size_t)32 * SEQ;

    // T14 prologue: tile 0 K/V into registers
    uint4 kr0 = *(const uint4*)kp0;  kp0 += (size_t)64 * HD;
    uint4 kr1 = *(const uint4*)kp1;  kp1 += (size_t)64 * HD;
    uint4 vr0 = *(const uint4*)vp0;  vp0 += 64;
    uint4 vr1 = *(const uint4*)vp1;  vp1 += 64;

    floatx4 acc_o[2][4];
    float lsum[2] = {0.f, 0.f};
    #pragma unroll
    for (int st = 0; st < 2; st++)
        #pragma unroll
        for (int dt = 0; dt < 4; dt++) acc_o[st][dt] = (floatx4){0.f, 0.f, 0.f, 0.f};

    for (int it = 0; it < 8; ++it) {
        const int cb = it & 1;
        // write this tile to buffer cb; previous reader of cb (iteration it-2)
        // is separated by iteration it-1's collective barrier -> WAR-safe.
        *(uint4*)&Ks[cb][sr][sc]       = kr0;
        *(uint4*)&Ks[cb][sr + 32][sc]  = kr1;
        *(uint4*)&Vts[cb][sr][sc]      = vr0;
        *(uint4*)&Vts[cb][sr + 32][sc] = vr1;
        if (it < 7) {                          // issue next-tile loads; hide under compute
            kr0 = *(const uint4*)kp0;  kp0 += (size_t)64 * HD;
            kr1 = *(const uint4*)kp1;  kp1 += (size_t)64 * HD;
            vr0 = *(const uint4*)vp0;  vp0 += 64;
            vr1 = *(const uint4*)vp1;  vp1 += 64;
        }
        asm volatile("s_waitcnt lgkmcnt(0)" ::: "memory");   // own ds_writes drained
        __builtin_amdgcn_s_barrier();          // all stores to buf cb visible

        short4v pa[2][4];
        #pragma unroll
        for (int st = 0; st < 2; st++) {
            floatx4 sacc[4];
            #pragma unroll
            for (int c = 0; c < 4; c++) sacc[c] = (floatx4){0.f, 0.f, 0.f, 0.f};
            #pragma unroll
            for (int kk = 0; kk < 2; kk++)
                #pragma unroll
                for (int c = 0; c < 4; c++) {
                    bf16x8 kf = *(const bf16x8*)&Ks[cb][c * 16 + lane16][kk * 32 + quad * 8];
                    sacc[c] = __builtin_amdgcn_mfma_f32_16x16x32_bf16(kf, qreg[st][kk], sacc[c], 0, 0, 0);
                }
            #pragma unroll
            for (int c = 0; c < 4; c++) {
                short4v pk;
                #pragma unroll
                for (int i = 0; i < 4; i++) {
                    float pv = exp2f(sacc[c][i] * SL2E);
                    lsum[st] += pv;
                    pk[i] = (short)f2bf(pv);
                }
                pa[st][c] = pk;
            }
        }
        #pragma unroll
        for (int c = 0; c < 4; c++) {
            #pragma unroll
            for (int dt = 0; dt < 4; dt++) {
                short4v vf = *(const short4v*)&Vts[cb][dt * 16 + lane16][c * 16 + quad * 4];
                #pragma unroll
                for (int st = 0; st < 2; st++)
                    acc_o[st][dt] = __builtin_amdgcn_mfma_f32_16x16x16bf16_1k(
                        vf, pa[st][c], acc_o[st][dt], 0, 0, 0);
            }
        }
    }

    const int b = bh >> 4, h = bh & 15;
    #pragma unroll
    for (int st = 0; st < 2; st++) {
        float rs = lsum[st];
        rs += __shfl_xor(rs, 16, 64);
        rs += __shfl_xor(rs, 32, 64);
        float inv = 1.0f / rs;
        int s = q0 + st * 64 + w * 16 + lane16;
        size_t rowbase = (size_t)(b * SEQ + s) * DIM + h * HD;
        #pragma unroll
        for (int dt = 0; dt < 4; dt++) {
            floatx4 v = acc_o[st][dt];
            uint2 o = { pk2(v[0] * inv, v[1] * inv), pk2(v[2] * inv, v[3] * inv) };
            *(uint2*)&Out[rowbase + dt * 16 + quad * 4] = o;
        }
    }
}

// ---------------------------------------------------------------------------
extern "C" void kernel_launch(void* const* d_in, const int* in_sizes, int n_in,
                              void* d_out, int out_size, void* d_ws, size_t ws_size,
                              hipStream_t stream)
{
    const float* x   = (const float*)d_in[0];
    const float* ctx = (const float*)d_in[1];
    const float* Wq  = (const float*)d_in[2];
    const float* Wk  = (const float*)d_in[3];
    const float* Wv  = (const float*)d_in[4];
    const float* Wo  = (const float*)d_in[5];
    const float* bo  = (const float*)d_in[6];

    const size_t NW = (size_t)DIM * DIM;      // 1M elems
    const size_t NB = (size_t)MROWS * DIM;    // 8.4M elems

    unsigned short* x_bf   = (unsigned short*)d_ws;   // 16.8 MB (reused as Ab)
    unsigned short* ctx_bf = x_bf + NB;               // 16.8 MB
    unsigned short* WqT    = ctx_bf + NB;             // 2 MB each
    unsigned short* WkT    = WqT + NW;
    unsigned short* WvT    = WkT + NW;
    unsigned short* WoT    = WvT + NW;
    unsigned short* Kb     = WoT + NW;                // 16.8 MB
    unsigned short* Vtb    = Kb + NB;                 // 16.8 MB
    float2*         cstab  = (float2*)(Vtb + NB);     // 256 KB — total ~75.5 MB
    unsigned short* Qb     = (unsigned short*)d_out;  // scratch: d_out (33.5 MB) holds
                                                      // bf16 Q until out_gemm overwrites
    unsigned short* Ab     = x_bf;                    // alias: x_bf dead after proj_qkv

    prep<<<12416, 256, 0, stream>>>(x, ctx, Wq, Wk, Wv, Wo,
                                    x_bf, ctx_bf, WqT, WkT, WvT, WoT, cstab);

    proj_qkv<<<1536, 256, 0, stream>>>(x_bf, ctx_bf, WqT, WkT, WvT,
                                       Qb, Kb, Vtb, cstab);

    attn_v4<<<1024, 256, 0, stream>>>(Qb, Kb, Vtb, Ab);

    out_gemm<<<512, 512, 0, stream>>>(Ab, WoT, (float*)d_out, bo);
}